// Round 1
// baseline (742.717 us; speedup 1.0000x reference)
//
#include <hip/hip_runtime.h>
#include <hip/hip_bf16.h>
#include <cstdint>
#include <cstddef>

#define L_SEQ 4096
#define BATCH_N 4
#define HID 1024
#define DH 256
// log2(0.96875) = log2(31/32)
#define LOG2_GAMMA (-0.045803689613124953f)

// ---------------------------------------------------------------------------
// Kernel 1: fused QKV projection GEMM (fp32) + xpos epilogue on Q/K.
//   X: (16384, 1024)  W*: (1024, 256)  -> Q,K,V: (16384, 256)
// Block: 256 threads, tile 64(M) x 64(N) x 16(K), 4x4 microtile/thread.
// grid.y = 12: [0..3]->Q cols 0..255, [4..7]->K, [8..11]->V.
// ---------------------------------------------------------------------------
__global__ __launch_bounds__(256) void qkv_xpos_kernel(
    const float* __restrict__ X,
    const float* __restrict__ WQ,
    const float* __restrict__ WK,
    const float* __restrict__ WV,
    float* __restrict__ Qo,
    float* __restrict__ Ko,
    float* __restrict__ Vo)
{
    __shared__ float As[16][68];   // A transposed: As[k][m], pad 68 (2-way max)
    __shared__ float Bs[16][64];   // Bs[k][n]

    const int m0  = blockIdx.x * 64;
    const int nt  = blockIdx.y;            // 0..11
    const int seg = nt >> 2;               // 0=Q, 1=K, 2=V
    const int n0  = (nt & 3) * 64;         // col offset within 256-wide segment
    const float* __restrict__ W   = (seg == 0) ? WQ : (seg == 1) ? WK : WV;
    float* __restrict__       Out = (seg == 0) ? Qo : (seg == 1) ? Ko : Vo;

    const int t  = threadIdx.x;
    const int tx = t & 15;
    const int ty = t >> 4;

    // global-load mapping
    const int ra = t >> 2;          // A row 0..63
    const int ka = (t & 3) * 4;     // A k   0,4,8,12
    const int kb = t >> 4;          // B k   0..15
    const int nb = (t & 15) * 4;    // B n   0..60

    float acc[4][4];
    #pragma unroll
    for (int i = 0; i < 4; ++i)
        #pragma unroll
        for (int j = 0; j < 4; ++j) acc[i][j] = 0.0f;

    for (int k0 = 0; k0 < HID; k0 += 16) {
        const float4 av = *(const float4*)&X[(size_t)(m0 + ra) * HID + k0 + ka];
        const float4 bv = *(const float4*)&W[(size_t)(k0 + kb) * DH + n0 + nb];
        __syncthreads();                 // previous tile's compute done
        As[ka + 0][ra] = av.x;
        As[ka + 1][ra] = av.y;
        As[ka + 2][ra] = av.z;
        As[ka + 3][ra] = av.w;
        *(float4*)&Bs[kb][nb] = bv;
        __syncthreads();

        #pragma unroll
        for (int kk = 0; kk < 16; ++kk) {
            const float4 a = *(const float4*)&As[kk][ty * 4];
            const float4 b = *(const float4*)&Bs[kk][tx * 4];
            const float aa[4] = {a.x, a.y, a.z, a.w};
            const float bb[4] = {b.x, b.y, b.z, b.w};
            #pragma unroll
            for (int i = 0; i < 4; ++i)
                #pragma unroll
                for (int j = 0; j < 4; ++j)
                    acc[i][j] += aa[i] * bb[j];
        }
    }

    // Epilogue: V stores raw; Q/K get xpos (rotary * per-dim positional scale).
    #pragma unroll
    for (int i = 0; i < 4; ++i) {
        const int gm  = m0 + ty * 4 + i;       // 0..16383
        const int pos = gm & (L_SEQ - 1);      // sequence position
        float* orow = Out + (size_t)gm * DH;
        const int dn = n0 + tx * 4;            // segment-local col of acc[i][0]
        if (seg == 2) {
            *(float4*)&orow[dn] =
                make_float4(acc[i][0], acc[i][1], acc[i][2], acc[i][3]);
        } else {
            const float e = (float)pos * (1.0f / 512.0f);
            float res[4];
            #pragma unroll
            for (int p = 0; p < 4; p += 2) {
                const int d  = dn + p;          // even col
                const int i2 = d >> 1;
                // scale_buf = (d + 0.4*256)/(1.4*256); scale = scale_buf^(pos/512)
                const float sb = ((float)d + 102.4f) * (1.0f / 358.4f);
                float sc = exp2f(log2f(sb) * e);
                if (seg == 1) sc = 1.0f / sc;   // downscale for K
                // inv_freq = 10000^(-i2/128); theta = pos * inv_freq
                const float invf =
                    exp2f(-13.287712379549449f * ((float)i2 * (1.0f / 128.0f)));
                const float th = (float)pos * invf;
                float s, c;
                sincosf(th, &s, &c);
                const float cs = c * sc, ss = s * sc;
                const float xe = acc[i][p], xo = acc[i][p + 1];
                res[p]     = xe * cs - xo * ss;
                res[p + 1] = xo * cs + xe * ss;
            }
            *(float4*)&orow[dn] = make_float4(res[0], res[1], res[2], res[3]);
        }
    }
}

// ---------------------------------------------------------------------------
// Kernel 2: windowed retention (flash-style, fp32).
//   out[b,q,:] = sum_{k in [q-543, q], k<=q} gamma^(q-k) (Q_q . K_k) V_k
// gamma^512 ~ 8.7e-8 -> truncation error ~4e-8 << 2.5e-4 threshold.
// Block: 256 threads, BQ=32 query rows; iterates 32-row K/V tiles.
// Thread t: r = t>>3 (row), cg = t&7 (32-col strip of O / 4-col strip of S).
// ---------------------------------------------------------------------------
__global__ __launch_bounds__(256) void retention_kernel(
    const float* __restrict__ Q,
    const float* __restrict__ K,
    const float* __restrict__ V,
    float* __restrict__ O)
{
    __shared__ float Qs[32][260];   // pad 260: conflict-free rotated reads
    __shared__ float Ks[32][260];
    __shared__ float Vs[32][260];
    __shared__ float Ss[32][33];

    const int qt = blockIdx.x;          // 0..127
    const int b  = blockIdx.y;          // 0..3
    const int t  = threadIdx.x;
    const int q0 = qt * 32;
    const size_t base = (size_t)b * L_SEQ * DH;

    const int r  = t >> 3;              // 0..31
    const int cg = t & 7;               // 0..7
    const int c0 = cg * 32;

    // stage Q tile (32 x 256)
    {
        const float* src = Q + base + (size_t)q0 * DH;
        #pragma unroll
        for (int i = 0; i < 8; ++i) {
            const int idx = i * 256 + t;
            const int row = idx >> 6;
            const int col = (idx & 63) * 4;
            *(float4*)&Qs[row][col] = *(const float4*)&src[row * DH + col];
        }
    }

    float o[32];
    #pragma unroll
    for (int j = 0; j < 32; ++j) o[j] = 0.0f;

    const int qpos = q0 + r;
    int kstart = q0 - 512;
    if (kstart < 0) kstart = 0;

    for (int k0 = kstart; k0 <= q0; k0 += 32) {
        __syncthreads();    // previous tile fully consumed (and Q visible, iter 0)
        {
            const float* ksrc = K + base + (size_t)k0 * DH;
            const float* vsrc = V + base + (size_t)k0 * DH;
            #pragma unroll
            for (int i = 0; i < 8; ++i) {
                const int idx = i * 256 + t;
                const int row = idx >> 6;
                const int col = (idx & 63) * 4;
                *(float4*)&Ks[row][col] = *(const float4*)&ksrc[row * DH + col];
                *(float4*)&Vs[row][col] = *(const float4*)&vsrc[row * DH + col];
            }
        }
        __syncthreads();

        // S[r][jj..jj+3] = Q[r,:] . K[jj+j,:]   (kk rotated by r: no conflicts)
        {
            const int jj = cg * 4;
            float a0 = 0.f, a1 = 0.f, a2 = 0.f, a3 = 0.f;
            #pragma unroll 8
            for (int kk = 0; kk < 64; ++kk) {
                const int kv = ((kk + r) & 63) * 4;
                const float4 qv  = *(const float4*)&Qs[r][kv];
                const float4 k0v = *(const float4*)&Ks[jj + 0][kv];
                const float4 k1v = *(const float4*)&Ks[jj + 1][kv];
                const float4 k2v = *(const float4*)&Ks[jj + 2][kv];
                const float4 k3v = *(const float4*)&Ks[jj + 3][kv];
                a0 += qv.x*k0v.x + qv.y*k0v.y + qv.z*k0v.z + qv.w*k0v.w;
                a1 += qv.x*k1v.x + qv.y*k1v.y + qv.z*k1v.z + qv.w*k1v.w;
                a2 += qv.x*k2v.x + qv.y*k2v.y + qv.z*k2v.z + qv.w*k2v.w;
                a3 += qv.x*k3v.x + qv.y*k3v.y + qv.z*k3v.z + qv.w*k3v.w;
            }
            const float av[4] = {a0, a1, a2, a3};
            #pragma unroll
            for (int j = 0; j < 4; ++j) {
                const int kp = k0 + jj + j;
                const int dd = qpos - kp;
                const float g = (dd >= 0) ? exp2f((float)dd * LOG2_GAMMA) : 0.0f;
                Ss[r][jj + j] = av[j] * g;
            }
        }
        __syncthreads();

        // O[r][c0..c0+31] += S[r][kv] * V[kv][c0..]   (kk rotated by cg)
        #pragma unroll 4
        for (int kk = 0; kk < 32; ++kk) {
            const int kv = (kk + cg) & 31;
            const float s = Ss[r][kv];
            const float* vrow = &Vs[kv][c0];
            #pragma unroll
            for (int jt = 0; jt < 8; ++jt) {
                const float4 v = *(const float4*)&vrow[jt * 4];
                o[jt*4+0] += s * v.x;
                o[jt*4+1] += s * v.y;
                o[jt*4+2] += s * v.z;
                o[jt*4+3] += s * v.w;
            }
        }
    }

    float* dst = O + base + (size_t)qpos * DH + c0;
    #pragma unroll
    for (int jt = 0; jt < 8; ++jt) {
        *(float4*)&dst[jt*4] =
            make_float4(o[jt*4+0], o[jt*4+1], o[jt*4+2], o[jt*4+3]);
    }
}

// ---------------------------------------------------------------------------
extern "C" void kernel_launch(void* const* d_in, const int* in_sizes, int n_in,
                              void* d_out, int out_size, void* d_ws, size_t ws_size,
                              hipStream_t stream)
{
    const float* X  = (const float*)d_in[0];
    const float* WQ = (const float*)d_in[1];
    const float* WK = (const float*)d_in[2];
    const float* WV = (const float*)d_in[3];
    float* out = (float*)d_out;

    const size_t per = (size_t)BATCH_N * L_SEQ * DH;  // 4,194,304 floats = 16 MB
    float* Qw = (float*)d_ws;
    float* Kw = Qw + per;
    float* Vw = Kw + per;   // total 48 MB of workspace

    dim3 g1((BATCH_N * L_SEQ) / 64, 12);
    qkv_xpos_kernel<<<g1, 256, 0, stream>>>(X, WQ, WK, WV, Qw, Kw, Vw);

    dim3 g2(L_SEQ / 32, BATCH_N);
    retention_kernel<<<g2, 256, 0, stream>>>(Qw, Kw, Vw, out);
}

// Round 2
// 450.323 us; speedup vs baseline: 1.6493x; 1.6493x over previous
//
#include <hip/hip_runtime.h>
#include <hip/hip_bf16.h>
#include <cstdint>
#include <cstddef>

#define L_SEQ 4096
#define BATCH_N 4
#define HID 1024
#define DH 256
// log2(0.96875)
#define LOG2_GAMMA (-0.045803689613124953f)

typedef __attribute__((ext_vector_type(8))) short short8;
typedef __attribute__((ext_vector_type(4))) float floatx4;

__device__ __forceinline__ unsigned short f2bf(float f) {
    union { float f; unsigned int u; } v; v.f = f;
    unsigned int r = (v.u + 0x7FFFu + ((v.u >> 16) & 1u)) >> 16;  // RNE
    return (unsigned short)r;
}

// ---------------------------------------------------------------------------
// Kernel 1: fused QKV projection GEMM (fp32 compute) + xpos epilogue.
// Outputs: Qo, Ko row-major bf16 [16384][256]; V transposed bf16 Vt[b*256+c][4096].
// ---------------------------------------------------------------------------
__global__ __launch_bounds__(256) void qkv_xpos_kernel(
    const float* __restrict__ X,
    const float* __restrict__ WQ,
    const float* __restrict__ WK,
    const float* __restrict__ WV,
    unsigned short* __restrict__ Qo,
    unsigned short* __restrict__ Ko,
    unsigned short* __restrict__ VtG)
{
    __shared__ float As[16][68];
    __shared__ float Bs[16][64];

    const int m0  = blockIdx.x * 64;
    const int nt  = blockIdx.y;            // 0..11
    const int seg = nt >> 2;               // 0=Q, 1=K, 2=V
    const int n0  = (nt & 3) * 64;
    const float* __restrict__ W = (seg == 0) ? WQ : (seg == 1) ? WK : WV;

    const int t  = threadIdx.x;
    const int tx = t & 15;
    const int ty = t >> 4;

    const int ra = t >> 2;
    const int ka = (t & 3) * 4;
    const int kb = t >> 4;
    const int nb = (t & 15) * 4;

    float acc[4][4];
    #pragma unroll
    for (int i = 0; i < 4; ++i)
        #pragma unroll
        for (int j = 0; j < 4; ++j) acc[i][j] = 0.0f;

    for (int k0 = 0; k0 < HID; k0 += 16) {
        const float4 av = *(const float4*)&X[(size_t)(m0 + ra) * HID + k0 + ka];
        const float4 bv = *(const float4*)&W[(size_t)(k0 + kb) * DH + n0 + nb];
        __syncthreads();
        As[ka + 0][ra] = av.x;
        As[ka + 1][ra] = av.y;
        As[ka + 2][ra] = av.z;
        As[ka + 3][ra] = av.w;
        *(float4*)&Bs[kb][nb] = bv;
        __syncthreads();

        #pragma unroll
        for (int kk = 0; kk < 16; ++kk) {
            const float4 a = *(const float4*)&As[kk][ty * 4];
            const float4 b = *(const float4*)&Bs[kk][tx * 4];
            const float aa[4] = {a.x, a.y, a.z, a.w};
            const float bb[4] = {b.x, b.y, b.z, b.w};
            #pragma unroll
            for (int i = 0; i < 4; ++i)
                #pragma unroll
                for (int j = 0; j < 4; ++j)
                    acc[i][j] += aa[i] * bb[j];
        }
    }

    #pragma unroll
    for (int i = 0; i < 4; ++i) {
        const int gm  = m0 + ty * 4 + i;       // 0..16383
        const int b   = gm >> 12;
        const int pos = gm & (L_SEQ - 1);
        const int dn  = n0 + tx * 4;
        if (seg == 2) {
            // V: transposed store Vt[b*256 + c][pos]
            #pragma unroll
            for (int j = 0; j < 4; ++j) {
                VtG[(((size_t)(b * 256 + dn + j)) << 12) + pos] = f2bf(acc[i][j]);
            }
        } else {
            unsigned short* orow =
                ((seg == 0) ? Qo : Ko) + (size_t)gm * DH;
            const float e = (float)pos * (1.0f / 512.0f);
            float res[4];
            #pragma unroll
            for (int p = 0; p < 4; p += 2) {
                const int d  = dn + p;
                const int i2 = d >> 1;
                const float sb = ((float)d + 102.4f) * (1.0f / 358.4f);
                float sc = exp2f(log2f(sb) * e);
                if (seg == 1) sc = 1.0f / sc;
                const float invf =
                    exp2f(-13.287712379549449f * ((float)i2 * (1.0f / 128.0f)));
                const float th = (float)pos * invf;
                float s, c;
                sincosf(th, &s, &c);
                const float cs = c * sc, ss = s * sc;
                const float xe = acc[i][p], xo = acc[i][p + 1];
                res[p]     = xe * cs - xo * ss;
                res[p + 1] = xo * cs + xe * ss;
            }
            ushort4 pk;
            pk.x = f2bf(res[0]); pk.y = f2bf(res[1]);
            pk.z = f2bf(res[2]); pk.w = f2bf(res[3]);
            *(ushort4*)&orow[dn] = pk;
        }
    }
}

// ---------------------------------------------------------------------------
// Kernel 2: windowed retention via bf16 MFMA (16x16x32), fp32 accumulate.
//   Q-tile 64 rows/block (wave w owns rows w*16..w*16+15), K-tile 32 keys.
//   S = Q.K^T -> decay in C-layout regs -> P(bf16)->LDS -> PV MFMA.
// ---------------------------------------------------------------------------
__global__ __launch_bounds__(256) void retention_kernel(
    const unsigned short* __restrict__ Q,
    const unsigned short* __restrict__ K,
    const unsigned short* __restrict__ VtG,
    float* __restrict__ O)
{
    __shared__ short Qs[64][264];   // 33792 B, stride 528B (16B-aligned rows)
    __shared__ short Ks[32][264];   // 16896 B
    __shared__ short Vt[256][40];   // 20480 B  [col][key], stride 80B
    __shared__ short Ss[64][40];    //  5120 B  [q][key]

    const int qt = blockIdx.x;          // 0..63
    const int b  = blockIdx.y;          // 0..3
    const int t  = threadIdx.x;
    const int q0 = qt * 64;

    const int w    = t >> 6;            // wave 0..3
    const int lane = t & 63;
    const int quad = lane >> 4;
    const int l16  = lane & 15;
    const int w16  = w * 16;

    const size_t rbase = (size_t)b * L_SEQ * DH;   // row-major Q/K base
    const size_t vbase = ((size_t)b * DH) << 12;   // Vt base: (b*256 + c)*4096

    // stage Q tile: 64 x 256 bf16
    {
        const unsigned short* src = Q + rbase + (size_t)q0 * DH;
        #pragma unroll
        for (int i = 0; i < 8; ++i) {
            const int row = i * 8 + (t >> 5);
            const int col = (t & 31) * 8;
            *(uint4*)&Qs[row][col] = *(const uint4*)&src[row * DH + col];
        }
    }

    floatx4 o[16];
    #pragma unroll
    for (int f = 0; f < 16; ++f) o[f] = (floatx4){0.f, 0.f, 0.f, 0.f};

    int kstart = q0 - 512;
    if (kstart < 0) kstart = 0;

    for (int k0 = kstart; k0 < q0 + 64; k0 += 32) {
        __syncthreads();   // K/V/Ss from previous iteration fully consumed
        // stage K tile 32 x 256 (row-major)
        {
            const unsigned short* src = K + rbase + (size_t)k0 * DH;
            #pragma unroll
            for (int i = 0; i < 4; ++i) {
                const int row = i * 8 + (t >> 5);
                const int col = (t & 31) * 8;
                *(uint4*)&Ks[row][col] = *(const uint4*)&src[row * DH + col];
            }
        }
        // stage V^T tile: Vt[c][0..31] from global Vt[b*256+c][k0..k0+31]
        {
            const int koff = (t & 7) * 4;
            #pragma unroll
            for (int i = 0; i < 8; ++i) {
                const int c = (t >> 3) + 32 * i;
                *(uint2*)&Vt[c][koff] =
                    *(const uint2*)&VtG[vbase + ((size_t)c << 12) + k0 + koff];
            }
        }
        __syncthreads();

        // S = Q . K^T for this wave's 16 q-rows x 32 keys; decay; P -> Ss
        #pragma unroll
        for (int ntile = 0; ntile < 2; ++ntile) {
            floatx4 s = (floatx4){0.f, 0.f, 0.f, 0.f};
            #pragma unroll
            for (int d8 = 0; d8 < 8; ++d8) {
                const short8 a = *(const short8*)&Qs[w16 + l16][d8 * 32 + quad * 8];
                const short8 bfr = *(const short8*)&Ks[ntile * 16 + l16][d8 * 32 + quad * 8];
                s = __builtin_amdgcn_mfma_f32_16x16x32_bf16(a, bfr, s, 0, 0, 0);
            }
            const int kpos = k0 + ntile * 16 + l16;
            #pragma unroll
            for (int g = 0; g < 4; ++g) {
                const int qpos = q0 + w16 + quad * 4 + g;
                const int d = qpos - kpos;
                const float p = (d >= 0) ? s[g] * exp2f((float)d * LOG2_GAMMA) : 0.0f;
                Ss[w16 + quad * 4 + g][ntile * 16 + l16] = (short)f2bf(p);
            }
        }
        __syncthreads();

        // O += P . V  (A-frag = P from Ss, B-frags = Vt columns)
        {
            const short8 a = *(const short8*)&Ss[w16 + l16][quad * 8];
            #pragma unroll
            for (int f = 0; f < 16; ++f) {
                const short8 bfr = *(const short8*)&Vt[f * 16 + l16][quad * 8];
                o[f] = __builtin_amdgcn_mfma_f32_16x16x32_bf16(a, bfr, o[f], 0, 0, 0);
            }
        }
    }

    // epilogue: C-layout scatter (16 consecutive floats per quarter-wave)
    #pragma unroll
    for (int f = 0; f < 16; ++f) {
        #pragma unroll
        for (int g = 0; g < 4; ++g) {
            const int qpos = q0 + w16 + quad * 4 + g;
            O[rbase + (size_t)qpos * DH + f * 16 + l16] = o[f][g];
        }
    }
}

// ---------------------------------------------------------------------------
extern "C" void kernel_launch(void* const* d_in, const int* in_sizes, int n_in,
                              void* d_out, int out_size, void* d_ws, size_t ws_size,
                              hipStream_t stream)
{
    const float* X  = (const float*)d_in[0];
    const float* WQ = (const float*)d_in[1];
    const float* WK = (const float*)d_in[2];
    const float* WV = (const float*)d_in[3];
    float* out = (float*)d_out;

    const size_t per = (size_t)BATCH_N * L_SEQ * DH;  // 4,194,304 elems (bf16 -> 8MB)
    unsigned short* Qw  = (unsigned short*)d_ws;
    unsigned short* Kw  = Qw + per;
    unsigned short* Vtw = Kw + per;   // 24 MB total

    dim3 g1((BATCH_N * L_SEQ) / 64, 12);
    qkv_xpos_kernel<<<g1, 256, 0, stream>>>(X, WQ, WK, WV, Qw, Kw, Vtw);

    dim3 g2(L_SEQ / 64, BATCH_N);
    retention_kernel<<<g2, 256, 0, stream>>>(Qw, Kw, Vtw, out);
}

// Round 3
// 190.625 us; speedup vs baseline: 3.8962x; 2.3624x over previous
//
#include <hip/hip_runtime.h>
#include <hip/hip_bf16.h>
#include <cstdint>
#include <cstddef>

#define L_SEQ 4096
#define BATCH_N 4
#define HID 1024
#define DH 256
// log2(0.96875)
#define LOG2_GAMMA (-0.045803689613124953f)

typedef __attribute__((ext_vector_type(8))) short short8;
typedef __attribute__((ext_vector_type(4))) float floatx4;

__device__ __forceinline__ unsigned short f2bf(float f) {
    union { float f; unsigned int u; } v; v.f = f;
    unsigned int r = (v.u + 0x7FFFu + ((v.u >> 16) & 1u)) >> 16;  // RNE
    return (unsigned short)r;
}

__device__ __forceinline__ void async_copy16(const unsigned short* gsrc,
                                             unsigned short* lds) {
    __builtin_amdgcn_global_load_lds(
        (const __attribute__((address_space(1))) unsigned int*)gsrc,
        (__attribute__((address_space(3))) unsigned int*)lds, 16, 0, 0);
}

// ---------------------------------------------------------------------------
// Kernel A: X fp32 -> bf16
// ---------------------------------------------------------------------------
__global__ __launch_bounds__(256) void convert_x_kernel(
    const float* __restrict__ X, unsigned short* __restrict__ Xb)
{
    const int i = (blockIdx.x * 256 + threadIdx.x) * 4;
    const float4 v = *(const float4*)&X[i];
    ushort4 p;
    p.x = f2bf(v.x); p.y = f2bf(v.y); p.z = f2bf(v.z); p.w = f2bf(v.w);
    *(ushort4*)&Xb[i] = p;
}

// ---------------------------------------------------------------------------
// Kernel B: W_{Q,K,V} (1024x256 fp32 each) -> Wt bf16 [768][1024] (transposed,
// concatenated: rows 0..255 = Q feats, 256..511 = K, 512..767 = V)
// ---------------------------------------------------------------------------
__global__ __launch_bounds__(256) void transpose_w_kernel(
    const float* __restrict__ WQ, const float* __restrict__ WK,
    const float* __restrict__ WV, unsigned short* __restrict__ Wt)
{
    __shared__ float Ts[64][68];   // [n_local][k_local]
    const int n0 = blockIdx.x * 64;     // 0..704
    const int k0 = blockIdx.y * 64;     // 0..960
    const int seg = n0 >> 8;
    const float* __restrict__ W = (seg == 0) ? WQ : (seg == 1) ? WK : WV;
    const int nl0 = n0 & 255;

    const int t  = threadIdx.x;
    const int r  = t >> 4;          // 0..15
    const int c4 = (t & 15) * 4;
    #pragma unroll
    for (int i = 0; i < 4; ++i) {
        const int kk = r + i * 16;
        const float4 v = *(const float4*)&W[(size_t)(k0 + kk) * DH + nl0 + c4];
        Ts[c4 + 0][kk] = v.x;
        Ts[c4 + 1][kk] = v.y;
        Ts[c4 + 2][kk] = v.z;
        Ts[c4 + 3][kk] = v.w;
    }
    __syncthreads();
    const int rn = t >> 3;          // 0..31
    const int c8 = (t & 7) * 8;
    #pragma unroll
    for (int i = 0; i < 2; ++i) {
        const int rr = rn + i * 32;
        ushort4 p0, p1;
        p0.x = f2bf(Ts[rr][c8 + 0]); p0.y = f2bf(Ts[rr][c8 + 1]);
        p0.z = f2bf(Ts[rr][c8 + 2]); p0.w = f2bf(Ts[rr][c8 + 3]);
        p1.x = f2bf(Ts[rr][c8 + 4]); p1.y = f2bf(Ts[rr][c8 + 5]);
        p1.z = f2bf(Ts[rr][c8 + 6]); p1.w = f2bf(Ts[rr][c8 + 7]);
        unsigned short* dst = &Wt[(size_t)(n0 + rr) * HID + k0 + c8];
        *(ushort4*)dst       = p0;
        *(ushort4*)(dst + 4) = p1;
    }
}

// ---------------------------------------------------------------------------
// Kernel C: QKV projection via bf16 MFMA, output-transposed D[n][pos].
//   A = Wt rows (feature n, k), B = Xb rows (pos, k). 128x128 tile, BK=32.
//   C-layout: row(=feature) = quad*4+reg (4 consecutive feats per lane ->
//   xpos pairs lane-local), col(=pos) = l16.
//   Epilogue: seg Q/K -> xpos -> row-major bf16 Qo/Ko[pos][256];
//             seg V  -> direct transposed store Vt[b*256+c][pos].
// ---------------------------------------------------------------------------
__global__ __launch_bounds__(256) void gemm_qkv_kernel(
    const unsigned short* __restrict__ Wt,   // [768][1024]
    const unsigned short* __restrict__ Xb,   // [16384][1024]
    unsigned short* __restrict__ Qo,
    unsigned short* __restrict__ Ko,
    unsigned short* __restrict__ VtG)
{
    __shared__ unsigned short Wa[128][32];   // 8 KB  [n][k]
    __shared__ unsigned short Xs[128][32];   // 8 KB  [pos][k]

    const int n0 = blockIdx.x * 128;   // 0..640
    const int p0 = blockIdx.y * 128;   // 0..16256
    const int t    = threadIdx.x;
    const int w    = t >> 6;
    const int lane = t & 63;
    const int quad = lane >> 4;
    const int l16  = lane & 15;
    const int wn   = (w & 1) * 64;
    const int wp   = (w >> 1) * 64;

    const int srow = w * 32 + (lane >> 2);   // staging row (+is*16)
    const int scol = (lane & 3) * 8;         // staging col (shorts)

    floatx4 acc[4][4];
    #pragma unroll
    for (int i = 0; i < 4; ++i)
        #pragma unroll
        for (int j = 0; j < 4; ++j) acc[i][j] = (floatx4){0.f, 0.f, 0.f, 0.f};

    for (int k0 = 0; k0 < HID; k0 += 32) {
        __syncthreads();   // previous tile's frag reads complete
        #pragma unroll
        for (int is = 0; is < 2; ++is) {
            const unsigned short* ga =
                &Wt[(size_t)(n0 + srow + is * 16) * HID + k0 + scol];
            const unsigned short* gb =
                &Xb[(size_t)(p0 + srow + is * 16) * HID + k0 + scol];
            async_copy16(ga, &Wa[w * 32 + is * 16][0]);
            async_copy16(gb, &Xs[w * 32 + is * 16][0]);
        }
        __syncthreads();   // staging visible

        short8 af[4], bf[4];
        #pragma unroll
        for (int nt = 0; nt < 4; ++nt)
            af[nt] = *(const short8*)&Wa[wn + nt * 16 + l16][quad * 8];
        #pragma unroll
        for (int pt = 0; pt < 4; ++pt)
            bf[pt] = *(const short8*)&Xs[wp + pt * 16 + l16][quad * 8];
        #pragma unroll
        for (int nt = 0; nt < 4; ++nt)
            #pragma unroll
            for (int pt = 0; pt < 4; ++pt)
                acc[nt][pt] = __builtin_amdgcn_mfma_f32_16x16x32_bf16(
                    af[nt], bf[pt], acc[nt][pt], 0, 0, 0);
    }

    // ---- epilogue ----
    const int seg = n0 >> 8;     // 0=Q 1=K 2=V
    #pragma unroll
    for (int nt = 0; nt < 4; ++nt) {
        const int nfeat = n0 + wn + nt * 16 + quad * 4;  // feat of reg g=0
        const int d0 = nfeat & 255;                      // segment-local
        #pragma unroll
        for (int pt = 0; pt < 4; ++pt) {
            const int pg  = p0 + wp + pt * 16 + l16;     // global row
            const int b   = pg >> 12;
            const int pos = pg & (L_SEQ - 1);
            if (seg == 2) {
                #pragma unroll
                for (int g = 0; g < 4; ++g)
                    VtG[(((size_t)(b * 256 + d0 + g)) << 12) + pos] =
                        f2bf(acc[nt][pt][g]);
            } else {
                const float e = (float)pos * (1.0f / 512.0f);
                float res[4];
                #pragma unroll
                for (int h = 0; h < 4; h += 2) {
                    const int d  = d0 + h;
                    const int i2 = d >> 1;
                    const float sb = ((float)d + 102.4f) * (1.0f / 358.4f);
                    float sc = exp2f(log2f(sb) * e);
                    if (seg == 1) sc = 1.0f / sc;
                    const float invf = exp2f(-13.287712379549449f *
                                             ((float)i2 * (1.0f / 128.0f)));
                    float s, c;
                    sincosf((float)pos * invf, &s, &c);
                    const float cs = c * sc, ss = s * sc;
                    const float xe = acc[nt][pt][h], xo = acc[nt][pt][h + 1];
                    res[h]     = xe * cs - xo * ss;
                    res[h + 1] = xo * cs + xe * ss;
                }
                ushort4 pk;
                pk.x = f2bf(res[0]); pk.y = f2bf(res[1]);
                pk.z = f2bf(res[2]); pk.w = f2bf(res[3]);
                unsigned short* orow =
                    ((seg == 0) ? Qo : Ko) + (size_t)pg * DH + d0;
                *(ushort4*)orow = pk;
            }
        }
    }
}

// ---------------------------------------------------------------------------
// Kernel D: windowed retention via bf16 MFMA (unchanged from round 2).
// ---------------------------------------------------------------------------
__global__ __launch_bounds__(256) void retention_kernel(
    const unsigned short* __restrict__ Q,
    const unsigned short* __restrict__ K,
    const unsigned short* __restrict__ VtG,
    float* __restrict__ O)
{
    __shared__ short Qs[64][264];
    __shared__ short Ks[32][264];
    __shared__ short Vt[256][40];
    __shared__ short Ss[64][40];

    const int qt = blockIdx.x;
    const int b  = blockIdx.y;
    const int t  = threadIdx.x;
    const int q0 = qt * 64;

    const int w    = t >> 6;
    const int lane = t & 63;
    const int quad = lane >> 4;
    const int l16  = lane & 15;
    const int w16  = w * 16;

    const size_t rbase = (size_t)b * L_SEQ * DH;
    const size_t vbase = ((size_t)b * DH) << 12;

    {
        const unsigned short* src = Q + rbase + (size_t)q0 * DH;
        #pragma unroll
        for (int i = 0; i < 8; ++i) {
            const int row = i * 8 + (t >> 5);
            const int col = (t & 31) * 8;
            *(uint4*)&Qs[row][col] = *(const uint4*)&src[row * DH + col];
        }
    }

    floatx4 o[16];
    #pragma unroll
    for (int f = 0; f < 16; ++f) o[f] = (floatx4){0.f, 0.f, 0.f, 0.f};

    int kstart = q0 - 512;
    if (kstart < 0) kstart = 0;

    for (int k0 = kstart; k0 < q0 + 64; k0 += 32) {
        __syncthreads();
        {
            const unsigned short* src = K + rbase + (size_t)k0 * DH;
            #pragma unroll
            for (int i = 0; i < 4; ++i) {
                const int row = i * 8 + (t >> 5);
                const int col = (t & 31) * 8;
                *(uint4*)&Ks[row][col] = *(const uint4*)&src[row * DH + col];
            }
        }
        {
            const int koff = (t & 7) * 4;
            #pragma unroll
            for (int i = 0; i < 8; ++i) {
                const int c = (t >> 3) + 32 * i;
                *(uint2*)&Vt[c][koff] =
                    *(const uint2*)&VtG[vbase + ((size_t)c << 12) + k0 + koff];
            }
        }
        __syncthreads();

        #pragma unroll
        for (int ntile = 0; ntile < 2; ++ntile) {
            floatx4 s = (floatx4){0.f, 0.f, 0.f, 0.f};
            #pragma unroll
            for (int d8 = 0; d8 < 8; ++d8) {
                const short8 a   = *(const short8*)&Qs[w16 + l16][d8 * 32 + quad * 8];
                const short8 bfr = *(const short8*)&Ks[ntile * 16 + l16][d8 * 32 + quad * 8];
                s = __builtin_amdgcn_mfma_f32_16x16x32_bf16(a, bfr, s, 0, 0, 0);
            }
            const int kpos = k0 + ntile * 16 + l16;
            #pragma unroll
            for (int g = 0; g < 4; ++g) {
                const int qpos = q0 + w16 + quad * 4 + g;
                const int d = qpos - kpos;
                const float p = (d >= 0) ? s[g] * exp2f((float)d * LOG2_GAMMA) : 0.0f;
                Ss[w16 + quad * 4 + g][ntile * 16 + l16] = (short)f2bf(p);
            }
        }
        __syncthreads();

        {
            const short8 a = *(const short8*)&Ss[w16 + l16][quad * 8];
            #pragma unroll
            for (int f = 0; f < 16; ++f) {
                const short8 bfr = *(const short8*)&Vt[f * 16 + l16][quad * 8];
                o[f] = __builtin_amdgcn_mfma_f32_16x16x32_bf16(a, bfr, o[f], 0, 0, 0);
            }
        }
    }

    #pragma unroll
    for (int f = 0; f < 16; ++f) {
        #pragma unroll
        for (int g = 0; g < 4; ++g) {
            const int qpos = q0 + w16 + quad * 4 + g;
            O[rbase + (size_t)qpos * DH + f * 16 + l16] = o[f][g];
        }
    }
}

// ---------------------------------------------------------------------------
extern "C" void kernel_launch(void* const* d_in, const int* in_sizes, int n_in,
                              void* d_out, int out_size, void* d_ws, size_t ws_size,
                              hipStream_t stream)
{
    const float* X  = (const float*)d_in[0];
    const float* WQ = (const float*)d_in[1];
    const float* WK = (const float*)d_in[2];
    const float* WV = (const float*)d_in[3];
    float* out = (float*)d_out;

    const size_t per = (size_t)BATCH_N * L_SEQ * DH;   // 4,194,304
    unsigned short* Qw  = (unsigned short*)d_ws;
    unsigned short* Kw  = Qw + per;
    unsigned short* Vtw = Kw + per;
    unsigned short* Xbw = Vtw + per;                   // 16,777,216 elems
    unsigned short* Wtw = Xbw + (size_t)16384 * HID;   // 786,432 elems
    // total workspace: ~60.3 MB

    convert_x_kernel<<<16384, 256, 0, stream>>>(X, Xbw);
    transpose_w_kernel<<<dim3(12, 16), 256, 0, stream>>>(WQ, WK, WV, Wtw);

    gemm_qkv_kernel<<<dim3(6, 128), 256, 0, stream>>>(Wtw, Xbw, Qw, Kw, Vtw);

    retention_kernel<<<dim3(L_SEQ / 64, BATCH_N), 256, 0, stream>>>(Qw, Kw, Vtw, out);
}